// Round 7
// baseline (396.371 us; speedup 1.0000x reference)
//
#include <hip/hip_runtime.h>
#include <stdint.h>

// Problem constants
#define F_     128
#define N_     12288
#define NH_    9
#define NSLOT_ 8
#define NVARS_ 8
#define NUP_   (4*N_)
#define K6_    (NH_*F_)   // 1152

typedef __attribute__((ext_vector_type(8))) short bf16x8;
typedef __attribute__((ext_vector_type(4))) float f32x4;

typedef const __attribute__((address_space(1))) unsigned char* gp1_t;
typedef __attribute__((address_space(3))) unsigned char* lp3_t;

__device__ __forceinline__ void load16(const void* g, void* l) {
  __builtin_amdgcn_global_load_lds((gp1_t)g, (lp3_t)l, 16, 0, 0);
}

__device__ __forceinline__ unsigned short f2bf(float f) {
  union { float f; unsigned int u; } x; x.f = f;
  unsigned int u = x.u;
  unsigned int r = u + 0x7FFFu + ((u >> 16) & 1u);   // RNE
  return (unsigned short)(r >> 16);
}

// ---------------- converts ----------------
__global__ void k_conv_emb(const float4* __restrict__ src, ushort4* __restrict__ dst, int n4) {
  int i = blockIdx.x * blockDim.x + threadIdx.x;
  if (i >= n4) return;
  float4 v = src[i];
  ushort4 o;
  o.x = f2bf(v.x); o.y = f2bf(v.y); o.z = f2bf(v.z); o.w = f2bf(v.w);
  dst[i] = o;
}

// dst[j*rows + k] = bf16(src[k*cols + j]) ; dst is [cols][rows]
__global__ void k_transpose_bf(const float* __restrict__ src, unsigned short* __restrict__ dst,
                               int rows, int cols) {
  int i = blockIdx.x * blockDim.x + threadIdx.x;
  if (i >= rows * cols) return;
  int j = i / rows, k = i % rows;
  dst[i] = f2bf(src[k * cols + j]);
}

// ---------------- zoom 5 (round-6 version, var-dedup, slot-outer epilogue) ----------------
__global__ __launch_bounds__(256) void k_h5(
    const unsigned short* __restrict__ embB,
    const unsigned short* __restrict__ W5T,
    const float* __restrict__ b5,
    const float* __restrict__ x5,
    const int* __restrict__ var_idx,
    const int* __restrict__ adjc,
    float* __restrict__ y5)
{
  const int slot = blockIdx.y;
  const int var = var_idx[slot];
  for (int j = 0; j < NSLOT_; ++j) {
    if (j >= slot) break;
    if (var_idx[j] == var) return;
  }
  unsigned int fmask = 0;
  for (int j = slot; j < NSLOT_; ++j)
    if (var_idx[j] == var) fmask |= 1u << j;

  __shared__ __align__(1024) unsigned char smem[8192 + 32768 + 64*4];
  unsigned char* Asm = smem;
  unsigned char* Bsm = smem + 8192;
  int* ald = (int*)(smem + 8192 + 32768);

  const int tid = threadIdx.x;
  const int l = tid & 63, w = tid >> 6;
  const int wr = w >> 1, wc = w & 1;
  const int li8 = l >> 3, pc = l & 7, l15 = l & 15, l16 = l >> 4;

  const int nt = blockIdx.x;
  const int n0 = nt * 64;

  if (tid < 64) ald[tid] = adjc[(n0 + tid) * NH_];
  __syncthreads();

  const f32x4 fz = {0.f, 0.f, 0.f, 0.f};
  f32x4 accS[2][4], accH[2][4];
#pragma unroll
  for (int mf = 0; mf < 2; ++mf)
#pragma unroll
    for (int nf = 0; nf < 4; ++nf) { accS[mf][nf] = fz; accH[mf][nf] = fz; }

  const size_t embVarOff = (size_t)var * ((size_t)N_ * F_);

  for (int step = 0; step < 2; ++step) {
    const int k0 = step << 6;
#pragma unroll
    for (int q2 = 0; q2 < 2; ++q2) {
      const int q = w * 2 + q2;
      const int r = q * 8 + li8;
      const int lc = pc ^ (r & 7);
      const unsigned short* g = embB + embVarOff + (size_t)ald[r] * F_ + k0 + lc * 8;
      load16(g, Asm + q * 1024);
    }
#pragma unroll
    for (int q2 = 0; q2 < 8; ++q2) {
      const int q = w * 8 + q2;
      const int j = q * 8 + li8;
      const int lc = pc ^ (j & 7);
      const unsigned short* g = W5T + (size_t)j * F_ + k0 + lc * 8;
      load16(g, Bsm + q * 1024);
    }
    __syncthreads();

#pragma unroll
    for (int kf = 0; kf < 2; ++kf) {
      const int kc = kf * 4 + l16;
      bf16x8 a[2], bs[4], bh[4];
#pragma unroll
      for (int mf = 0; mf < 2; ++mf) {
        const int r = wr * 32 + mf * 16 + l15;
        a[mf] = *(const bf16x8*)(Asm + r * 128 + ((kc ^ (r & 7)) << 4));
      }
#pragma unroll
      for (int nf = 0; nf < 4; ++nf) {
        const int js = wc * 64 + nf * 16 + l15;
        bs[nf] = *(const bf16x8*)(Bsm + js * 128 + ((kc ^ (js & 7)) << 4));
        const int jh = js + 128;
        bh[nf] = *(const bf16x8*)(Bsm + jh * 128 + ((kc ^ (jh & 7)) << 4));
      }
#pragma unroll
      for (int mf = 0; mf < 2; ++mf)
#pragma unroll
        for (int nf = 0; nf < 4; ++nf) {
          accS[mf][nf] = __builtin_amdgcn_mfma_f32_16x16x32_bf16(a[mf], bs[nf], accS[mf][nf], 0, 0, 0);
          accH[mf][nf] = __builtin_amdgcn_mfma_f32_16x16x32_bf16(a[mf], bh[nf], accH[mf][nf], 0, 0, 0);
        }
    }
    __syncthreads();
  }

  for (int j = slot; j < NSLOT_; ++j) {
    if (!(fmask & (1u << j))) continue;
    const size_t sbase = (size_t)j * ((size_t)N_ * F_);
#pragma unroll
    for (int mf = 0; mf < 2; ++mf)
#pragma unroll
      for (int nf = 0; nf < 4; ++nf) {
        const int f = wc * 64 + nf * 16 + l15;
        const float sb = b5[f];
        const float hb = b5[128 + f];
#pragma unroll
        for (int reg = 0; reg < 4; ++reg) {
          const int r = wr * 32 + mf * 16 + l16 * 4 + reg;
          const size_t idx = sbase + ((size_t)(n0 + r)) * F_ + f;
          y5[idx] = x5[idx] * (accS[mf][nf][reg] + sb) + (accH[mf][nf][reg] + hb);
        }
      }
  }
}

// ---------------- zoom 6: 256x256 tile, m201-style 8-phase K-loop + var-dedup ----------------
// 8 waves (2M x 4N): per wave rows {mh*128 + wr*64 ..+64}, cols {wc*32 (S), 128+wc*32 (H)}.
// 18 K-tiles of BK=64 = 9 iterations x 2 K-tiles (ta=2i buf0, tb=2i+1 buf1).
// Per phase: ds-reads + exactly ONE half-tile stage; vmcnt(6) ONLY at ph4/ph8.
// Stage slots: ph1:A1h1(tb) ph2:A0h0(ta+2) ph3:B0h0 ph4:B0h1 ph5:A0h1 ph6:A1h0(tb+2) ph7:B1h0 ph8:B1h1
// Consumption: ph1:{A0h0,B0h0} ph2:{B0h1} ph3:{A0h1} ph5:{A1h0,B1h0} ph6:{B1h1} ph7:{A1h1}
// Checkpoint vmcnt(6)=3 halves: every consumed half is >=4 stage-slots old -> guaranteed landed.
__global__ __launch_bounds__(512, 2) void k_h6(
    const unsigned short* __restrict__ embB,   // [NVARS][N][F] bf16
    const unsigned short* __restrict__ W6T,    // [1024][1152] bf16 (transposed W6)
    const float* __restrict__ b6,              // [1024]
    const float* __restrict__ x6,              // [NSLOT][NUP][F]
    const int* __restrict__ var_idx,
    const int* __restrict__ adjc,              // [N][9]
    float* __restrict__ y6)                    // [NSLOT][NUP][F]
{
  const int slot = blockIdx.z;
  const int var = var_idx[slot];
  for (int j = 0; j < NSLOT_; ++j) {
    if (j >= slot) break;
    if (var_idx[j] == var) return;            // uniform, before any barrier
  }
  unsigned int fmask = 0;
  for (int j = slot; j < NSLOT_; ++j)
    if (var_idx[j] == var) fmask |= 1u << j;

  __shared__ __align__(1024) unsigned char smem[131072 + 256*NH_*4];
  unsigned char* Asm0 = smem;                  // 2 bufs x [256 rows x 128B] (swizzled)
  unsigned char* Bsm0 = smem + 65536;          // 2 bufs x [256 rows x 128B]
  int* ald = (int*)(smem + 131072);            // 256 x 9

  const int tid = threadIdx.x;
  const int l = tid & 63, w = tid >> 6;        // 8 waves
  const int wr = w >> 2, wc = w & 3;           // 2 x 4
  const int li8 = l >> 3, pc = l & 7, l15 = l & 15, l16 = l >> 4;

  const int nt = blockIdx.x;                   // 0..47
  const int ct = blockIdx.y;                   // 0..3
  const int n0 = nt * 256;
  const int col0 = ct * 256;
  const char* embBase = (const char*)(embB + (size_t)var * ((size_t)N_ * F_));
  const char* W6Tb = (const char*)W6T;

  for (int t2 = tid; t2 < 256 * NH_; t2 += 512) ald[t2] = adjc[n0 * NH_ + t2];
  __syncthreads();

  const unsigned int LCC = (unsigned int)((pc ^ li8) << 4);   // swizzled chunk byte
  const int r0 = w * 16 + li8;                 // A/B half0 rows (local)
  const int r1 = r0 + 8;
  const int r2 = 128 + r0;                     // half1 rows
  const int r3 = r2 + 8;
  const unsigned int jb00 = (unsigned int)(col0 + r0) * (K6_ * 2) + LCC;
  const unsigned int jb01 = (unsigned int)(col0 + r1) * (K6_ * 2) + LCC;
  const unsigned int jb10 = (unsigned int)(col0 + r2) * (K6_ * 2) + LCC;
  const unsigned int jb11 = (unsigned int)(col0 + r3) * (K6_ * 2) + LCC;

#define STAGE_A(av_0, av_1, kkb, hh, bb) do {                                     \
    load16(embBase + (av_0) + (kkb) + LCC,                                        \
           Asm0 + (bb) * 32768 + (hh) * 16384 + (w * 2) * 1024);                  \
    load16(embBase + (av_1) + (kkb) + LCC,                                        \
           Asm0 + (bb) * 32768 + (hh) * 16384 + (w * 2 + 1) * 1024);              \
  } while (0)

#define STAGE_B(jb_0, jb_1, kb, hh, bb) do {                                      \
    load16(W6Tb + (jb_0) + (kb),                                                  \
           Bsm0 + (bb) * 32768 + (hh) * 16384 + (w * 2) * 1024);                  \
    load16(W6Tb + (jb_1) + (kb),                                                  \
           Bsm0 + (bb) * 32768 + (hh) * 16384 + (w * 2 + 1) * 1024);              \
  } while (0)

#define LDA(dst, mh, Ab) do {                                                     \
    _Pragma("unroll")                                                             \
    for (int mq_ = 0; mq_ < 4; ++mq_)                                             \
    _Pragma("unroll")                                                             \
    for (int kf_ = 0; kf_ < 2; ++kf_) {                                           \
      const int r_ = (mh) * 128 + wr * 64 + mq_ * 16 + l15;                       \
      const int kc_ = kf_ * 4 + l16;                                              \
      dst[mq_][kf_] = *(const bf16x8*)((Ab) + r_ * 128 + ((kc_ ^ (r_ & 7)) << 4)); \
    } } while (0)

#define LDB(dst, jofs, Bb) do {                                                   \
    _Pragma("unroll")                                                             \
    for (int nf_ = 0; nf_ < 2; ++nf_)                                             \
    _Pragma("unroll")                                                             \
    for (int kf_ = 0; kf_ < 2; ++kf_) {                                           \
      const int j_ = (jofs) + wc * 32 + nf_ * 16 + l15;                           \
      const int kc_ = kf_ * 4 + l16;                                              \
      dst[nf_][kf_] = *(const bf16x8*)((Bb) + j_ * 128 + ((kc_ ^ (j_ & 7)) << 4)); \
    } } while (0)

#define MM(acc, mh, af, bfr) do {                                                 \
    _Pragma("unroll")                                                             \
    for (int mq_ = 0; mq_ < 4; ++mq_)                                             \
    _Pragma("unroll")                                                             \
    for (int nf_ = 0; nf_ < 2; ++nf_)                                             \
    _Pragma("unroll")                                                             \
    for (int kf_ = 0; kf_ < 2; ++kf_)                                             \
      acc[(mh)*4+mq_][nf_] = __builtin_amdgcn_mfma_f32_16x16x32_bf16(             \
          af[mq_][kf_], bfr[nf_][kf_], acc[(mh)*4+mq_][nf_], 0, 0, 0);            \
    } while (0)

#define VMW6   asm volatile("s_waitcnt vmcnt(6)" ::: "memory")
#define LGK0   do { asm volatile("s_waitcnt lgkmcnt(0)" ::: "memory"); \
                    __builtin_amdgcn_sched_barrier(0); } while (0)
#define BAR    __builtin_amdgcn_s_barrier()
#define PRIO1  __builtin_amdgcn_s_setprio(1)
#define PRIO0  __builtin_amdgcn_s_setprio(0)

  const f32x4 fz = {0.f, 0.f, 0.f, 0.f};
  f32x4 accS[8][2], accH[8][2];
#pragma unroll
  for (int mf = 0; mf < 8; ++mf)
#pragma unroll
    for (int nf = 0; nf < 2; ++nf) { accS[mf][nf] = fz; accH[mf][nf] = fz; }

  // index regs: h=0 for all 4 rows
  unsigned int c0 = ((unsigned int)ald[r0 * NH_ + 0]) << 8;
  unsigned int c1 = ((unsigned int)ald[r1 * NH_ + 0]) << 8;
  unsigned int c2 = ((unsigned int)ald[r2 * NH_ + 0]) << 8;
  unsigned int c3 = ((unsigned int)ald[r3 * NH_ + 0]) << 8;

  // prologue: 7 halves in steady-state age order
  STAGE_A(c0, c1, 0,   0, 0);     // A0h0 (t=0)
  STAGE_B(jb00, jb01, 0, 0, 0);   // B0h0
  STAGE_B(jb10, jb11, 0, 1, 0);   // B0h1
  STAGE_A(c2, c3, 0,   1, 0);     // A0h1
  STAGE_A(c0, c1, 128, 0, 1);     // A1h0 (t=1)
  STAGE_B(jb00, jb01, 128, 0, 1); // B1h0
  STAGE_B(jb10, jb11, 128, 1, 1); // B1h1
  VMW6;
  BAR;

  const unsigned char* Ab0 = Asm0;
  const unsigned char* Ab1 = Asm0 + 32768;
  const unsigned char* Bb0 = Bsm0;
  const unsigned char* Bb1 = Bsm0 + 32768;

#pragma unroll 1
  for (int i = 0; i < 9; ++i) {
    const int hn = (i < 8) ? (i + 1) : 8;              // next h (clamped for junk iter)
    const int sa = (i < 8) ? (2 * i + 2) : 0;          // buf0 stage K-tile
    const int sb = (i < 8) ? (2 * i + 3) : 1;          // buf1 stage K-tile
    const unsigned int kba = (unsigned int)(sa << 7);
    const unsigned int kbb = (unsigned int)(sb << 7);

    bf16x8 a[4][2], bS[2][2], bH[2][2];

    // ph1: consume ta {A0h0,B0h0}; load next-h indices; stage A1h1 (t=2i+1, h=i)
    LDA(a, 0, Ab0);
    LDB(bS, 0, Bb0);
    const unsigned int i0 = ((unsigned int)ald[r0 * NH_ + hn]) << 8;
    const unsigned int i1 = ((unsigned int)ald[r1 * NH_ + hn]) << 8;
    const unsigned int i2 = ((unsigned int)ald[r2 * NH_ + hn]) << 8;
    const unsigned int i3 = ((unsigned int)ald[r3 * NH_ + hn]) << 8;
    STAGE_A(c2, c3, 128, 1, 1);
    BAR; LGK0;
    PRIO1; MM(accS, 0, a, bS); PRIO0;
    BAR;

    // ph2: consume {B0h1}; stage A0h0 (t=sa, h=hn)
    LDB(bH, 128, Bb0);
    STAGE_A(i0, i1, 0, 0, 0);
    BAR; LGK0;
    PRIO1; MM(accH, 0, a, bH); PRIO0;
    BAR;

    // ph3: consume {A0h1}; stage B0h0
    LDA(a, 1, Ab0);
    STAGE_B(jb00, jb01, kba, 0, 0);
    BAR; LGK0;
    PRIO1; MM(accS, 1, a, bS); PRIO0;
    BAR;

    // ph4: stage B0h1; CHECKPOINT
    STAGE_B(jb10, jb11, kba, 1, 0);
    VMW6;
    BAR;
    PRIO1; MM(accH, 1, a, bH); PRIO0;
    BAR;

    // ph5: consume tb {A1h0,B1h0}; stage A0h1 (t=sa, h=hn)
    LDA(a, 0, Ab1);
    LDB(bS, 0, Bb1);
    STAGE_A(i2, i3, 0, 1, 0);
    BAR; LGK0;
    PRIO1; MM(accS, 0, a, bS); PRIO0;
    BAR;

    // ph6: consume {B1h1}; stage A1h0 (t=sb, h=hn)
    LDB(bH, 128, Bb1);
    STAGE_A(i0, i1, 128, 0, 1);
    BAR; LGK0;
    PRIO1; MM(accH, 0, a, bH); PRIO0;
    BAR;

    // ph7: consume {A1h1}; stage B1h0
    LDA(a, 1, Ab1);
    STAGE_B(jb00, jb01, kbb, 0, 1);
    BAR; LGK0;
    PRIO1; MM(accS, 1, a, bS); PRIO0;
    BAR;

    // ph8: stage B1h1; CHECKPOINT
    STAGE_B(jb10, jb11, kbb, 1, 1);
    VMW6;
    BAR;
    PRIO1; MM(accH, 1, a, bH); PRIO0;
    BAR;

    c2 = i2; c3 = i3;
  }
  asm volatile("s_waitcnt vmcnt(0)" ::: "memory");   // drain junk stages before LDS reuse
  __syncthreads();

  // ---- epilogue: scale/shift planes in LDS, float4 streaming FiLM, slot loop for MLP ----
  float* SP = (float*)smem;          // [128][128] f32
  float* HP = SP + 16384;            // [128][128] f32
#pragma unroll 1
  for (int mh = 0; mh < 2; ++mh) {
#pragma unroll
    for (int mq = 0; mq < 4; ++mq)
#pragma unroll
      for (int nf = 0; nf < 2; ++nf) {
        const int f = wc * 32 + nf * 16 + l15;
        const float sb = b6[col0 + f];
        const float hb = b6[col0 + 128 + f];
#pragma unroll
        for (int reg = 0; reg < 4; ++reg) {
          const int row = wr * 64 + mq * 16 + l16 * 4 + reg;
          SP[row * 128 + f] = accS[mh * 4 + mq][nf][reg] + sb;
          HP[row * 128 + f] = accH[mh * 4 + mq][nf][reg] + hb;
        }
      }
    __syncthreads();
#pragma unroll
    for (int it = 0; it < 8; ++it) {
      const int g = it * 512 + tid;          // 128 rows x 32 f4
      const int row = g >> 5, c4 = g & 31;
      const float4 s4 = *(const float4*)(SP + row * 128 + c4 * 4);
      const float4 h4 = *(const float4*)(HP + row * 128 + c4 * 4);
      const size_t nupf = ((size_t)(4 * (n0 + mh * 128 + row) + ct)) * F_ + c4 * 4;
      for (int j = slot; j < NSLOT_; ++j) {
        if (!(fmask & (1u << j))) continue;
        const size_t idx = (size_t)j * ((size_t)NUP_ * F_) + nupf;
        const float4 x = *(const float4*)(x6 + idx);
        float4 y;
        y.x = x.x * s4.x + h4.x;
        y.y = x.y * s4.y + h4.y;
        y.z = x.z * s4.z + h4.z;
        y.w = x.w * s4.w + h4.w;
        *(float4*)(y6 + idx) = y;
      }
    }
    if (mh == 0) __syncthreads();            // planes rewritten next pass
  }

#undef STAGE_A
#undef STAGE_B
#undef LDA
#undef LDB
#undef MM
#undef VMW6
#undef LGK0
#undef BAR
#undef PRIO1
#undef PRIO0
}

extern "C" void kernel_launch(void* const* d_in, const int* in_sizes, int n_in,
                              void* d_out, int out_size, void* d_ws, size_t ws_size,
                              hipStream_t stream) {
  (void)in_sizes; (void)n_in; (void)out_size; (void)ws_size;
  const float* emb = (const float*)d_in[0];
  const float* x5  = (const float*)d_in[1];
  const float* x6  = (const float*)d_in[2];
  const float* W5  = (const float*)d_in[3];
  const float* b5  = (const float*)d_in[4];
  const float* W6  = (const float*)d_in[5];
  const float* b6  = (const float*)d_in[6];
  const int* var_idx = (const int*)d_in[7];
  const int* adjc    = (const int*)d_in[8];

  float* y5 = (float*)d_out;
  float* y6 = y5 + (size_t)NSLOT_ * N_ * F_;

  unsigned short* embB = (unsigned short*)d_ws;
  unsigned short* W5T  = embB + (size_t)NVARS_ * N_ * F_;
  unsigned short* W6T  = W5T + 256 * 128;

  const int embN4 = NVARS_ * N_ * F_ / 4;
  k_conv_emb<<<(embN4 + 255) / 256, 256, 0, stream>>>((const float4*)emb, (ushort4*)embB, embN4);
  k_transpose_bf<<<(128 * 256 + 255) / 256, 256, 0, stream>>>(W5, W5T, 128, 256);
  k_transpose_bf<<<(1152 * 1024 + 255) / 256, 256, 0, stream>>>(W6, W6T, 1152, 1024);

  k_h5<<<dim3(N_ / 64, NSLOT_), 256, 0, stream>>>(embB, W5T, b5, x5, var_idx, adjc, y5);
  k_h6<<<dim3(48, 4, 8), 512, 0, stream>>>(embB, W6T, b6, x6, var_idx, adjc, y6);
}

// Round 8
// 266.362 us; speedup vs baseline: 1.4881x; 1.4881x over previous
//
#include <hip/hip_runtime.h>
#include <stdint.h>

// Problem constants
#define F_     128
#define N_     12288
#define NH_    9
#define NSLOT_ 8
#define NVARS_ 8
#define NUP_   (4*N_)
#define K6_    (NH_*F_)   // 1152

typedef __attribute__((ext_vector_type(8))) short bf16x8;
typedef __attribute__((ext_vector_type(4))) float f32x4;

typedef const __attribute__((address_space(1))) unsigned char* gp1_t;
typedef __attribute__((address_space(3))) unsigned char* lp3_t;

__device__ __forceinline__ void load16(const void* g, void* l) {
  __builtin_amdgcn_global_load_lds((gp1_t)g, (lp3_t)l, 16, 0, 0);
}

__device__ __forceinline__ unsigned short f2bf(float f) {
  union { float f; unsigned int u; } x; x.f = f;
  unsigned int u = x.u;
  unsigned int r = u + 0x7FFFu + ((u >> 16) & 1u);   // RNE
  return (unsigned short)(r >> 16);
}

// ---------------- converts ----------------
__global__ void k_conv_emb(const float4* __restrict__ src, ushort4* __restrict__ dst, int n4) {
  int i = blockIdx.x * blockDim.x + threadIdx.x;
  if (i >= n4) return;
  float4 v = src[i];
  ushort4 o;
  o.x = f2bf(v.x); o.y = f2bf(v.y); o.z = f2bf(v.z); o.w = f2bf(v.w);
  dst[i] = o;
}

// dst[j*rows + k] = bf16(src[k*cols + j]) ; dst is [cols][rows]
__global__ void k_transpose_bf(const float* __restrict__ src, unsigned short* __restrict__ dst,
                               int rows, int cols) {
  int i = blockIdx.x * blockDim.x + threadIdx.x;
  if (i >= rows * cols) return;
  int j = i / rows, k = i % rows;
  dst[i] = f2bf(src[k * cols + j]);
}

// ---------------- zoom 5: var-dedup GEMM + plane epilogue ----------------
// block: 64 rows x 256 cols, 256 thr (4 waves: 2 wr x 2 wc), BK=64, 2 k-steps
__global__ __launch_bounds__(256) void k_h5(
    const unsigned short* __restrict__ embB,   // [NVARS][N][F] bf16
    const unsigned short* __restrict__ W5T,    // [256][128]  bf16 (transposed W5)
    const float* __restrict__ b5,              // [256]
    const float* __restrict__ x5,              // [NSLOT][N][F]
    const int* __restrict__ var_idx,           // [NSLOT]
    const int* __restrict__ adjc,              // [N][9]
    float* __restrict__ y5)                    // [NSLOT][N][F]
{
  const int slot = blockIdx.y;
  const int var = var_idx[slot];
  for (int j = 0; j < NSLOT_; ++j) {
    if (j >= slot) break;
    if (var_idx[j] == var) return;            // uniform per block, before any barrier
  }
  unsigned int fmask = 0;
  for (int j = slot; j < NSLOT_; ++j)
    if (var_idx[j] == var) fmask |= 1u << j;

  __shared__ __align__(1024) unsigned char smem[8192 + 32768 + 64*4];
  unsigned char* Asm = smem;                 // 64 rows x 128 B (swizzled)
  unsigned char* Bsm = smem + 8192;          // 256 rows x 128 B (swizzled)
  int* ald = (int*)(smem + 8192 + 32768);

  const int tid = threadIdx.x;
  const int l = tid & 63, w = tid >> 6;
  const int wr = w >> 1, wc = w & 1;
  const int li8 = l >> 3, pc = l & 7, l15 = l & 15, l16 = l >> 4;

  const int nt = blockIdx.x;
  const int n0 = nt * 64;

  if (tid < 64) ald[tid] = adjc[(n0 + tid) * NH_];   // self index (col 0)
  __syncthreads();

  const f32x4 fz = {0.f, 0.f, 0.f, 0.f};
  f32x4 accS[2][4], accH[2][4];
#pragma unroll
  for (int mf = 0; mf < 2; ++mf)
#pragma unroll
    for (int nf = 0; nf < 4; ++nf) { accS[mf][nf] = fz; accH[mf][nf] = fz; }

  const size_t embVarOff = (size_t)var * ((size_t)N_ * F_);

  for (int step = 0; step < 2; ++step) {
    const int k0 = step << 6;
#pragma unroll
    for (int q2 = 0; q2 < 2; ++q2) {
      const int q = w * 2 + q2;
      const int r = q * 8 + li8;
      const int lc = pc ^ (r & 7);
      const unsigned short* g = embB + embVarOff + (size_t)ald[r] * F_ + k0 + lc * 8;
      load16(g, Asm + q * 1024);
    }
#pragma unroll
    for (int q2 = 0; q2 < 8; ++q2) {
      const int q = w * 8 + q2;
      const int j = q * 8 + li8;
      const int lc = pc ^ (j & 7);
      const unsigned short* g = W5T + (size_t)j * F_ + k0 + lc * 8;
      load16(g, Bsm + q * 1024);
    }
    __syncthreads();

#pragma unroll
    for (int kf = 0; kf < 2; ++kf) {
      const int kc = kf * 4 + l16;
      bf16x8 a[2], bs[4], bh[4];
#pragma unroll
      for (int mf = 0; mf < 2; ++mf) {
        const int r = wr * 32 + mf * 16 + l15;
        a[mf] = *(const bf16x8*)(Asm + r * 128 + ((kc ^ (r & 7)) << 4));
      }
#pragma unroll
      for (int nf = 0; nf < 4; ++nf) {
        const int js = wc * 64 + nf * 16 + l15;
        bs[nf] = *(const bf16x8*)(Bsm + js * 128 + ((kc ^ (js & 7)) << 4));
        const int jh = js + 128;
        bh[nf] = *(const bf16x8*)(Bsm + jh * 128 + ((kc ^ (jh & 7)) << 4));
      }
#pragma unroll
      for (int mf = 0; mf < 2; ++mf)
#pragma unroll
        for (int nf = 0; nf < 4; ++nf) {
          accS[mf][nf] = __builtin_amdgcn_mfma_f32_16x16x32_bf16(a[mf], bs[nf], accS[mf][nf], 0, 0, 0);
          accH[mf][nf] = __builtin_amdgcn_mfma_f32_16x16x32_bf16(a[mf], bh[nf], accH[mf][nf], 0, 0, 0);
        }
    }
    __syncthreads();
  }

  // ---- plane epilogue: scale/shift -> LDS [32][132] (padded), float4 streaming FiLM ----
  float* SP = (float*)smem;                  // [32][132]
  float* HP = SP + 32 * 132;                 // [32][132]
#pragma unroll 1
  for (int mh = 0; mh < 2; ++mh) {           // 32-row halves; owned by waves wr==mh
    if (wr == mh) {
#pragma unroll
      for (int mf = 0; mf < 2; ++mf)
#pragma unroll
        for (int nf = 0; nf < 4; ++nf) {
          const int f = wc * 64 + nf * 16 + l15;
          const float sb = b5[f];
          const float hb = b5[128 + f];
#pragma unroll
          for (int reg = 0; reg < 4; ++reg) {
            const int rr = mf * 16 + l16 * 4 + reg;   // 0..31
            SP[rr * 132 + f] = accS[mf][nf][reg] + sb;
            HP[rr * 132 + f] = accH[mf][nf][reg] + hb;
          }
        }
    }
    __syncthreads();
#pragma unroll
    for (int it = 0; it < 4; ++it) {
      const int g = it * 256 + tid;          // 32 rows x 32 f4
      const int row = g >> 5, c4 = g & 31;
      const float4 s4 = *(const float4*)(SP + row * 132 + c4 * 4);
      const float4 h4 = *(const float4*)(HP + row * 132 + c4 * 4);
      const size_t nf4 = ((size_t)(n0 + mh * 32 + row)) * F_ + c4 * 4;
      for (int j = slot; j < NSLOT_; ++j) {
        if (!(fmask & (1u << j))) continue;
        const size_t idx = (size_t)j * ((size_t)N_ * F_) + nf4;
        const float4 x = *(const float4*)(x5 + idx);
        float4 y;
        y.x = x.x * s4.x + h4.x;
        y.y = x.y * s4.y + h4.y;
        y.z = x.z * s4.z + h4.z;
        y.w = x.w * s4.w + h4.w;
        *(float4*)(y5 + idx) = y;
      }
    }
    if (mh == 0) __syncthreads();
  }
}

// ---------------- zoom 6: round-1 2-barrier GEMM + var-dedup + plane epilogue ----------------
// block: 128 rows x 256 cols (one child ct), 512 thr (8 waves: 2 wr x 4 wc), BK=64, 18 steps
__global__ __launch_bounds__(512) void k_h6(
    const unsigned short* __restrict__ embB,   // [NVARS][N][F] bf16
    const unsigned short* __restrict__ W6T,    // [1024][1152] bf16 (transposed W6)
    const float* __restrict__ b6,              // [1024]
    const float* __restrict__ x6,              // [NSLOT][NUP][F]
    const int* __restrict__ var_idx,
    const int* __restrict__ adjc,              // [N][9]
    float* __restrict__ y6)                    // [NSLOT][NUP][F]
{
  const int slot = blockIdx.z;                // 0..7
  const int var = var_idx[slot];
  for (int j = 0; j < NSLOT_; ++j) {
    if (j >= slot) break;
    if (var_idx[j] == var) return;            // uniform per block, before any barrier
  }
  unsigned int fmask = 0;
  for (int j = slot; j < NSLOT_; ++j)
    if (var_idx[j] == var) fmask |= 1u << j;

  // union: GEMM layout (16K A + 32K B + 4.6K ald = 53.8K) vs epilogue planes (2x33.8K = 67.6K)
  __shared__ __align__(1024) unsigned char smem[2 * 64 * 132 * 4];
  unsigned char* Asm = smem;                  // 128 rows x 128 B (swizzled)
  unsigned char* Bsm = smem + 16384;          // 256 rows x 128 B (swizzled)
  int* ald = (int*)(smem + 16384 + 32768);    // 128 x 9 neighbor ids

  const int tid = threadIdx.x;
  const int l = tid & 63, w = tid >> 6;       // 8 waves
  const int wr = w >> 2, wc = w & 3;          // 2 x 4
  const int li8 = l >> 3, pc = l & 7, l15 = l & 15, l16 = l >> 4;

  const int nt = blockIdx.x;                  // 0..95
  const int ct = blockIdx.y;                  // child 0..3
  const int n0 = nt * 128;
  const int col0 = ct * 256;

  for (int t = tid; t < 128 * NH_; t += 512) ald[t] = adjc[n0 * NH_ + t];
  __syncthreads();

  const f32x4 fz = {0.f, 0.f, 0.f, 0.f};
  f32x4 accS[4][2], accH[4][2];
#pragma unroll
  for (int mf = 0; mf < 4; ++mf)
#pragma unroll
    for (int nf = 0; nf < 2; ++nf) { accS[mf][nf] = fz; accH[mf][nf] = fz; }

  const size_t embVarOff = (size_t)var * ((size_t)N_ * F_);

  for (int step = 0; step < K6_ / 64; ++step) {   // 18
    const int h = step >> 1;
    const int kk0 = (step & 1) << 6;              // offset within emb row (F=128)
    const int k0 = step << 6;                     // offset within W6T row (K=1152)

    // stage A: 16 chunks, 2 per wave (gathered rows)
#pragma unroll
    for (int q2 = 0; q2 < 2; ++q2) {
      const int q = w * 2 + q2;
      const int r = q * 8 + li8;                  // 0..127
      const int lc = pc ^ (r & 7);
      const int m = ald[r * NH_ + h];
      const unsigned short* g = embB + embVarOff + (size_t)m * F_ + kk0 + lc * 8;
      load16(g, Asm + q * 1024);
    }
    // stage B: 32 chunks, 4 per wave
#pragma unroll
    for (int q2 = 0; q2 < 4; ++q2) {
      const int q = w * 4 + q2;
      const int j = q * 8 + li8;                  // 0..255
      const int lc = pc ^ (j & 7);
      const unsigned short* g = W6T + (size_t)(col0 + j) * K6_ + k0 + lc * 8;
      load16(g, Bsm + q * 1024);
    }
    __syncthreads();

#pragma unroll
    for (int kf = 0; kf < 2; ++kf) {
      const int kc = kf * 4 + l16;
      bf16x8 a[4], bs[2], bh[2];
#pragma unroll
      for (int mf = 0; mf < 4; ++mf) {
        const int r = wr * 64 + mf * 16 + l15;
        a[mf] = *(const bf16x8*)(Asm + r * 128 + ((kc ^ (r & 7)) << 4));
      }
#pragma unroll
      for (int nf = 0; nf < 2; ++nf) {
        const int js = wc * 32 + nf * 16 + l15;
        bs[nf] = *(const bf16x8*)(Bsm + js * 128 + ((kc ^ (js & 7)) << 4));
        const int jh = js + 128;
        bh[nf] = *(const bf16x8*)(Bsm + jh * 128 + ((kc ^ (jh & 7)) << 4));
      }
#pragma unroll
      for (int mf = 0; mf < 4; ++mf)
#pragma unroll
        for (int nf = 0; nf < 2; ++nf) {
          accS[mf][nf] = __builtin_amdgcn_mfma_f32_16x16x32_bf16(a[mf], bs[nf], accS[mf][nf], 0, 0, 0);
          accH[mf][nf] = __builtin_amdgcn_mfma_f32_16x16x32_bf16(a[mf], bh[nf], accH[mf][nf], 0, 0, 0);
        }
    }
    __syncthreads();
  }

  // ---- plane epilogue: scale/shift -> LDS [64][132] (padded), float4 streaming FiLM ----
  // Wave (wr,wc) owns rows wr*64..+63, S-cols wc*32..+31 (H at +128). Padding 132 makes the
  // scalar plane write 2-way-conflict max (free, m136); reads/stores are float4 coalesced.
  float* SP = (float*)smem;                  // [64][132]
  float* HP = SP + 64 * 132;                 // [64][132]
#pragma unroll 1
  for (int mh = 0; mh < 2; ++mh) {           // 64-row halves; owned by waves wr==mh
    if (wr == mh) {
#pragma unroll
      for (int mf = 0; mf < 4; ++mf)
#pragma unroll
        for (int nf = 0; nf < 2; ++nf) {
          const int f = wc * 32 + nf * 16 + l15;
          const float sb = b6[col0 + f];
          const float hb = b6[col0 + 128 + f];
#pragma unroll
          for (int reg = 0; reg < 4; ++reg) {
            const int rr = mf * 16 + l16 * 4 + reg;   // 0..63
            SP[rr * 132 + f] = accS[mf][nf][reg] + sb;
            HP[rr * 132 + f] = accH[mf][nf][reg] + hb;
          }
        }
    }
    __syncthreads();
#pragma unroll
    for (int it = 0; it < 4; ++it) {
      const int g = it * 512 + tid;          // 64 rows x 32 f4
      const int row = g >> 5, c4 = g & 31;
      const float4 s4 = *(const float4*)(SP + row * 132 + c4 * 4);
      const float4 h4 = *(const float4*)(HP + row * 132 + c4 * 4);
      const size_t nupf = ((size_t)(4 * (n0 + mh * 64 + row) + ct)) * F_ + c4 * 4;
      for (int j = slot; j < NSLOT_; ++j) {
        if (!(fmask & (1u << j))) continue;
        const size_t idx = (size_t)j * ((size_t)NUP_ * F_) + nupf;
        const float4 x = *(const float4*)(x6 + idx);
        float4 y;
        y.x = x.x * s4.x + h4.x;
        y.y = x.y * s4.y + h4.y;
        y.z = x.z * s4.z + h4.z;
        y.w = x.w * s4.w + h4.w;
        *(float4*)(y6 + idx) = y;
      }
    }
    if (mh == 0) __syncthreads();            // planes rewritten next pass
  }
}

extern "C" void kernel_launch(void* const* d_in, const int* in_sizes, int n_in,
                              void* d_out, int out_size, void* d_ws, size_t ws_size,
                              hipStream_t stream) {
  (void)in_sizes; (void)n_in; (void)out_size; (void)ws_size;
  const float* emb = (const float*)d_in[0];
  const float* x5  = (const float*)d_in[1];
  const float* x6  = (const float*)d_in[2];
  const float* W5  = (const float*)d_in[3];
  const float* b5  = (const float*)d_in[4];
  const float* W6  = (const float*)d_in[5];
  const float* b6  = (const float*)d_in[6];
  const int* var_idx = (const int*)d_in[7];
  const int* adjc    = (const int*)d_in[8];

  float* y5 = (float*)d_out;
  float* y6 = y5 + (size_t)NSLOT_ * N_ * F_;

  unsigned short* embB = (unsigned short*)d_ws;                  // 12,582,912 bf16
  unsigned short* W5T  = embB + (size_t)NVARS_ * N_ * F_;        // 32,768 bf16
  unsigned short* W6T  = W5T + 256 * 128;                        // 1,179,648 bf16

  const int embN4 = NVARS_ * N_ * F_ / 4;
  k_conv_emb<<<(embN4 + 255) / 256, 256, 0, stream>>>((const float4*)emb, (ushort4*)embB, embN4);
  k_transpose_bf<<<(128 * 256 + 255) / 256, 256, 0, stream>>>(W5, W5T, 128, 256);
  k_transpose_bf<<<(1152 * 1024 + 255) / 256, 256, 0, stream>>>(W6, W6T, 1152, 1024);

  k_h6<<<dim3(N_ / 128, 4, NSLOT_), 512, 0, stream>>>(embB, W6T, b6, x6, var_idx, adjc, y6);
  k_h5<<<dim3(N_ / 64, NSLOT_), 256, 0, stream>>>(embB, W5T, b5, x5, var_idx, adjc, y5);
}